// Round 1
// baseline (176.586 us; speedup 1.0000x reference)
//
#include <hip/hip_runtime.h>

typedef unsigned short u16;
typedef __attribute__((ext_vector_type(8))) short short8;
typedef __attribute__((ext_vector_type(4))) float f32x4;

#define NN 8192
#define FIN 512
#define FO 200
#define FP 208
#define CO 20
#define CAP 256
#define ALPHA 0.2f

__device__ __forceinline__ u16 f2bf(float f){
  union { float f; unsigned u; } c; c.f = f;
  unsigned u = c.u;
  return (u16)((u + 0x7fffu + ((u >> 16) & 1u)) >> 16);
}
__device__ __forceinline__ float bf2f(u16 s){
  union { unsigned u; float f; } c; c.u = ((unsigned)s) << 16;
  return c.f;
}

// ---------------- K0: WbT (bf16, padded transpose) + wa1/wa2 = W@a1, W@a2 ----
__global__ void k_prep(const float* __restrict__ W, const float* __restrict__ a1,
                       const float* __restrict__ a2, u16* __restrict__ WbT,
                       float* __restrict__ wa){
  __shared__ float al[FO];
  int b = blockIdx.x;
  if (b < FP) {
    int c = b;
    for (int k = threadIdx.x; k < FIN; k += 256) {
      float v = (c < FO) ? W[(size_t)k*FO + c] : 0.f;
      WbT[(size_t)c*FIN + k] = f2bf(v);
    }
  } else {
    const float* a = (b == FP) ? a1 : a2;
    float* out = wa + (size_t)(b - FP)*FIN;
    for (int t = threadIdx.x; t < FO; t += 256) al[t] = a[t];
    __syncthreads();
    for (int k = threadIdx.x; k < FIN; k += 256) {
      const float* wr = W + (size_t)k*FO;
      float acc = 0.f;
      for (int f = 0; f < FO; f++) acc = fmaf(wr[f], al[f], acc);
      out[k] = acc;
    }
  }
}

// ---------------- K1: xb = bf16(x); f1 = x@wa1; f2 = x@wa2 -------------------
__launch_bounds__(256)
__global__ void k_xprep(const float* __restrict__ x, const float* __restrict__ wa,
                        u16* __restrict__ xb, float* __restrict__ f1,
                        float* __restrict__ f2){
  int tid = threadIdx.x, lane = tid & 63, wid = tid >> 6;
  int i = blockIdx.x * 4 + wid;
  const float4* xr = (const float4*)(x + (size_t)i * FIN);
  float4 xa = xr[lane];
  float4 xc = xr[lane + 64];
  ushort4 pa, pb;
  pa.x = f2bf(xa.x); pa.y = f2bf(xa.y); pa.z = f2bf(xa.z); pa.w = f2bf(xa.w);
  pb.x = f2bf(xc.x); pb.y = f2bf(xc.y); pb.z = f2bf(xc.z); pb.w = f2bf(xc.w);
  ushort4* xbo = (ushort4*)(xb + (size_t)i * FIN);
  xbo[lane] = pa; xbo[lane + 64] = pb;
  float4 w1a = ((const float4*)wa)[lane];
  float4 w1b = ((const float4*)wa)[lane + 64];
  float4 w2a = ((const float4*)(wa + FIN))[lane];
  float4 w2b = ((const float4*)(wa + FIN))[lane + 64];
  float s1 = xa.x*w1a.x + xa.y*w1a.y + xa.z*w1a.z + xa.w*w1a.w
           + xc.x*w1b.x + xc.y*w1b.y + xc.z*w1b.z + xc.w*w1b.w;
  float s2 = xa.x*w2a.x + xa.y*w2a.y + xa.z*w2a.z + xa.w*w2a.w
           + xc.x*w2b.x + xc.y*w2b.y + xc.z*w2b.z + xc.w*w2b.w;
  #pragma unroll
  for (int o = 32; o; o >>= 1) { s1 += __shfl_xor(s1, o); s2 += __shfl_xor(s2, o); }
  if (lane == 0) { f1[i] = s1; f2[i] = s2; }
}

// ---------------- K2: h = xb @ WbT^T via MFMA bf16, output hb (bf16) --------
__launch_bounds__(128)
__global__ void k_gemm(const u16* __restrict__ xb, const u16* __restrict__ WbT,
                       u16* __restrict__ hb){
  __shared__ __align__(16) u16 As[32 * 32];
  __shared__ __align__(16) u16 Bs[FP * 32];
  int tid = threadIdx.x, lane = tid & 63, wid = tid >> 6;
  int rb = blockIdx.x * 32;
  f32x4 acc[13];
  #pragma unroll
  for (int n = 0; n < 13; n++) acc[n] = (f32x4){0.f, 0.f, 0.f, 0.f};
  for (int k0 = 0; k0 < FIN; k0 += 32) {
    __syncthreads();
    {
      int r = tid >> 2, j = tid & 3;
      uint4 av = *(const uint4*)(xb + (size_t)(rb + r) * FIN + k0 + j * 8);
      *(uint4*)&As[r * 32 + (j ^ ((r >> 1) & 3)) * 8] = av;
    }
    for (int c = tid; c < FP * 4; c += 128) {
      int col = c >> 2, j = c & 3;
      uint4 bv = *(const uint4*)(WbT + (size_t)col * FIN + k0 + j * 8);
      *(uint4*)&Bs[col * 32 + (j ^ ((col >> 1) & 3)) * 8] = bv;
    }
    __syncthreads();
    int lr = wid * 16 + (lane & 15);
    int jr = lane >> 4;
    short8 af = *(const short8*)&As[lr * 32 + (jr ^ ((lr >> 1) & 3)) * 8];
    #pragma unroll
    for (int n = 0; n < 13; n++) {
      int col = n * 16 + (lane & 15);
      short8 bfv = *(const short8*)&Bs[col * 32 + (jr ^ ((col >> 1) & 3)) * 8];
      acc[n] = __builtin_amdgcn_mfma_f32_16x16x32_bf16(af, bfv, acc[n], 0, 0, 0);
    }
  }
  int rbase = rb + wid * 16 + 4 * (lane >> 4);
  int cb = lane & 15;
  #pragma unroll
  for (int n = 0; n < 13; n++) {
    int col = n * 16 + cb;
    if (col < FO) {
      #pragma unroll
      for (int q = 0; q < 4; q++)
        hb[(size_t)(rbase + q) * FO + col] = f2bf(acc[n][q]);
    }
  }
}

// ---------------- K3: per-row attention + h' = elu(att@h), cache sparse rep --
__launch_bounds__(256)
__global__ void k_attn(const float* __restrict__ support, const float* __restrict__ f1,
                       const float* __restrict__ f2, const u16* __restrict__ hb,
                       float* __restrict__ hp, int* __restrict__ nnzg,
                       u16* __restrict__ idxg, float* __restrict__ valg){
  int i = blockIdx.x;
  int tid = threadIdx.x, lane = tid & 63, wid = tid >> 6;
  __shared__ u16 s_idx[CAP];
  __shared__ float s_val[CAP];
  __shared__ float s_att[CAP];
  __shared__ float s_red[8];
  __shared__ int s_base[4];
  const float4* row4 = (const float4*)(support + (size_t)i * NN);
  float4 v[8];
  #pragma unroll
  for (int k = 0; k < 8; k++) v[k] = row4[tid + 256 * k];
  int cnt = 0;
  #pragma unroll
  for (int k = 0; k < 8; k++)
    cnt += (v[k].x > 0.f) + (v[k].y > 0.f) + (v[k].z > 0.f) + (v[k].w > 0.f);
  // deterministic exclusive prefix: wave scan + block scan
  int sc = cnt;
  #pragma unroll
  for (int o = 1; o < 64; o <<= 1) { int t2 = __shfl_up(sc, o); if (lane >= o) sc += t2; }
  if (lane == 63) s_base[wid] = sc;
  __syncthreads();
  int wbase = 0;
  for (int w = 0; w < wid; w++) wbase += s_base[w];
  int total = s_base[0] + s_base[1] + s_base[2] + s_base[3];
  int pos = wbase + sc - cnt;
  #pragma unroll
  for (int k = 0; k < 8; k++) {
    int cbase = (tid + 256 * k) * 4;
    if (v[k].x > 0.f && pos < CAP) { s_idx[pos] = (u16)(cbase + 0); s_val[pos] = v[k].x; pos++; }
    if (v[k].y > 0.f && pos < CAP) { s_idx[pos] = (u16)(cbase + 1); s_val[pos] = v[k].y; pos++; }
    if (v[k].z > 0.f && pos < CAP) { s_idx[pos] = (u16)(cbase + 2); s_val[pos] = v[k].z; pos++; }
    if (v[k].w > 0.f && pos < CAP) { s_idx[pos] = (u16)(cbase + 3); s_val[pos] = v[k].w; pos++; }
  }
  __syncthreads();
  int nnz = min(total, CAP);
  float fi = f1[i];
  float lmax = -1e30f;
  for (int jj = tid; jj < nnz; jj += 256) {
    float e = fi + f2[s_idx[jj]];
    e = e > 0.f ? e : ALPHA * e;
    s_att[jj] = e;
    lmax = fmaxf(lmax, e);
  }
  #pragma unroll
  for (int o = 32; o; o >>= 1) lmax = fmaxf(lmax, __shfl_xor(lmax, o));
  if (lane == 0) s_red[wid] = lmax;
  __syncthreads();
  float m = fmaxf(fmaxf(s_red[0], s_red[1]), fmaxf(s_red[2], s_red[3]));
  float lsum = 0.f;
  for (int jj = tid; jj < nnz; jj += 256) {
    float p = __expf(s_att[jj] - m);
    s_att[jj] = p;
    lsum += p;
  }
  #pragma unroll
  for (int o = 32; o; o >>= 1) lsum += __shfl_xor(lsum, o);
  if (lane == 0) s_red[4 + wid] = lsum;
  __syncthreads();
  float rs = 1.0f / (s_red[4] + s_red[5] + s_red[6] + s_red[7]);
  // persist sparse rep for the output pass
  for (int jj = tid; jj < nnz; jj += 256) {
    idxg[(size_t)i * CAP + jj] = s_idx[jj];
    valg[(size_t)i * CAP + jj] = s_val[jj];
  }
  if (tid == 0) nnzg[i] = nnz;
  // h'[i][d] = elu( rs * sum_j p_j * h[j][d] )
  if (tid < FO) {
    float acc = 0.f;
    int jj = 0;
    for (; jj + 4 <= nnz; jj += 4) {
      int j0 = s_idx[jj], j1 = s_idx[jj + 1], j2 = s_idx[jj + 2], j3 = s_idx[jj + 3];
      float w0 = s_att[jj], w1 = s_att[jj + 1], w2 = s_att[jj + 2], w3 = s_att[jj + 3];
      float h0 = bf2f(hb[(size_t)j0 * FO + tid]);
      float h1 = bf2f(hb[(size_t)j1 * FO + tid]);
      float h2 = bf2f(hb[(size_t)j2 * FO + tid]);
      float h3 = bf2f(hb[(size_t)j3 * FO + tid]);
      acc += w0 * h0 + w1 * h1 + w2 * h2 + w3 * h3;
    }
    for (; jj < nnz; jj++) acc += s_att[jj] * bf2f(hb[(size_t)s_idx[jj] * FO + tid]);
    acc *= rs;
    float r = acc > 0.f ? acc : expm1f(acc);
    hp[(size_t)i * FO + tid] = r;
  }
}

// ---------------- K4: g = h' @ W0 -------------------------------------------
__launch_bounds__(256)
__global__ void k_g(const float* __restrict__ hp, const float* __restrict__ W0,
                    float* __restrict__ g){
  __shared__ float w0s[FO * CO];
  for (int t = threadIdx.x; t < FO * CO; t += 256) w0s[t] = W0[t];
  __syncthreads();
  int t = threadIdx.x;
  if (t >= 240) return;
  int r = blockIdx.x * 12 + t / 20, c = t % 20;
  if (r >= NN) return;
  const float* hr = hp + (size_t)r * FO;
  float acc = 0.f;
  #pragma unroll 4
  for (int k = 0; k < FO; k++) acc = fmaf(hr[k], w0s[k * CO + c], acc);
  g[(size_t)r * CO + c] = acc;
}

// ---------------- K5: out = support @ g  (sparse rep) ------------------------
__launch_bounds__(256)
__global__ void k_out(const int* __restrict__ nnzg, const u16* __restrict__ idxg,
                      const float* __restrict__ valg, const float* __restrict__ g,
                      float* __restrict__ out){
  int tid = threadIdx.x, lane = tid & 63, wid = tid >> 6;
  int i = blockIdx.x * 4 + wid;
  int nnz = nnzg[i];
  const u16* ig = idxg + (size_t)i * CAP;
  const float* vg = valg + (size_t)i * CAP;
  int c = lane % 20, grp = lane / 20;
  float acc = 0.f;
  if (grp < 3) {
    for (int jj = grp; jj < nnz; jj += 3) {
      int j = ig[jj];
      acc += vg[jj] * g[(size_t)j * CO + c];
    }
  }
  float b1 = __shfl(acc, lane + 20);
  float b2 = __shfl(acc, lane + 40);
  if (lane < 20) out[(size_t)i * CO + lane] = acc + b1 + b2;
}

extern "C" void kernel_launch(void* const* d_in, const int* in_sizes, int n_in,
                              void* d_out, int out_size, void* d_ws, size_t ws_size,
                              hipStream_t stream) {
  (void)in_sizes; (void)n_in; (void)out_size; (void)ws_size;
  const float* x       = (const float*)d_in[0];
  const float* support = (const float*)d_in[1];
  const float* W       = (const float*)d_in[2];
  const float* a1      = (const float*)d_in[3];
  const float* a2      = (const float*)d_in[4];
  const float* W0      = (const float*)d_in[5];
  char* ws = (char*)d_ws;
  u16*   xb   = (u16*)  (ws + 0);           // 8192*512*2      = 8388608
  u16*   WbT  = (u16*)  (ws + 8388608);     // 208*512*2       = 212992
  float* wa   = (float*)(ws + 8601600);     // 1024*4          = 4096
  float* f1   = (float*)(ws + 8605696);     // 8192*4          = 32768
  float* f2   = (float*)(ws + 8638464);     // 8192*4          = 32768
  u16*   hb   = (u16*)  (ws + 8671232);     // 8192*200*2      = 3276800
  float* hp   = (float*)(ws + 11948032);    // 8192*200*4      = 6553600
  float* g    = (float*)(ws + 18501632);    // 8192*20*4       = 655360
  int*   nnzg = (int*)  (ws + 19156992);    // 8192*4          = 32768
  u16*   idxg = (u16*)  (ws + 19189760);    // 8192*256*2      = 4194304
  float* valg = (float*)(ws + 23384064);    // 8192*256*4      = 8388608
  float* outp = (float*)d_out;

  k_prep <<<FP + 2,        256, 0, stream>>>(W, a1, a2, WbT, wa);
  k_xprep<<<NN / 4,        256, 0, stream>>>(x, wa, xb, f1, f2);
  k_gemm <<<NN / 32,       128, 0, stream>>>(xb, WbT, hb);
  k_attn <<<NN,            256, 0, stream>>>(support, f1, f2, hb, hp, nnzg, idxg, valg);
  k_g    <<<(NN + 11) / 12, 256, 0, stream>>>(hp, W0, g);
  k_out  <<<NN / 4,        256, 0, stream>>>(nnzg, idxg, valg, g, outp);
}

// Round 2
// 144.018 us; speedup vs baseline: 1.2261x; 1.2261x over previous
//
#include <hip/hip_runtime.h>

typedef unsigned short u16;
typedef unsigned int u32;
typedef __attribute__((ext_vector_type(8))) short short8;
typedef __attribute__((ext_vector_type(4))) float f32x4;

#define NN 8192
#define FIN 512
#define FO 200
#define FP 208
#define CO 20
#define CAP 256
#define ALPHA 0.2f

__device__ __forceinline__ u16 f2bf(float f){
  union { float f; unsigned u; } c; c.f = f;
  unsigned u = c.u;
  return (u16)((u + 0x7fffu + ((u >> 16) & 1u)) >> 16);
}
__device__ __forceinline__ float bf2f(u16 s){
  union { unsigned u; float f; } c; c.u = ((unsigned)s) << 16;
  return c.f;
}

// ---------------- K0: WbT (bf16, padded transpose) + wa1/wa2 = W@a1, W@a2 ----
__global__ void k_prep(const float* __restrict__ W, const float* __restrict__ a1,
                       const float* __restrict__ a2, u16* __restrict__ WbT,
                       float* __restrict__ wa){
  __shared__ float al[FO];
  int b = blockIdx.x;
  if (b < FP) {
    int c = b;
    for (int k = threadIdx.x; k < FIN; k += 256) {
      float v = (c < FO) ? W[(size_t)k*FO + c] : 0.f;
      WbT[(size_t)c*FIN + k] = f2bf(v);
    }
  } else {
    const float* a = (b == FP) ? a1 : a2;
    float* out = wa + (size_t)(b - FP)*FIN;
    for (int t = threadIdx.x; t < FO; t += 256) al[t] = a[t];
    __syncthreads();
    for (int k = threadIdx.x; k < FIN; k += 256) {
      const float* wr = W + (size_t)k*FO;
      float acc = 0.f;
      for (int f = 0; f < FO; f++) acc = fmaf(wr[f], al[f], acc);
      out[k] = acc;
    }
  }
}

// ---------------- K1: xb = bf16(x); f1 = x@wa1; f2 = x@wa2 -------------------
__launch_bounds__(256)
__global__ void k_xprep(const float* __restrict__ x, const float* __restrict__ wa,
                        u16* __restrict__ xb, float* __restrict__ f1,
                        float* __restrict__ f2){
  int tid = threadIdx.x, lane = tid & 63, wid = tid >> 6;
  int i = blockIdx.x * 4 + wid;
  const float4* xr = (const float4*)(x + (size_t)i * FIN);
  float4 xa = xr[lane];
  float4 xc = xr[lane + 64];
  ushort4 pa, pb;
  pa.x = f2bf(xa.x); pa.y = f2bf(xa.y); pa.z = f2bf(xa.z); pa.w = f2bf(xa.w);
  pb.x = f2bf(xc.x); pb.y = f2bf(xc.y); pb.z = f2bf(xc.z); pb.w = f2bf(xc.w);
  ushort4* xbo = (ushort4*)(xb + (size_t)i * FIN);
  xbo[lane] = pa; xbo[lane + 64] = pb;
  float4 w1a = ((const float4*)wa)[lane];
  float4 w1b = ((const float4*)wa)[lane + 64];
  float4 w2a = ((const float4*)(wa + FIN))[lane];
  float4 w2b = ((const float4*)(wa + FIN))[lane + 64];
  float s1 = xa.x*w1a.x + xa.y*w1a.y + xa.z*w1a.z + xa.w*w1a.w
           + xc.x*w1b.x + xc.y*w1b.y + xc.z*w1b.z + xc.w*w1b.w;
  float s2 = xa.x*w2a.x + xa.y*w2a.y + xa.z*w2a.z + xa.w*w2a.w
           + xc.x*w2b.x + xc.y*w2b.y + xc.z*w2b.z + xc.w*w2b.w;
  #pragma unroll
  for (int o = 32; o; o >>= 1) { s1 += __shfl_xor(s1, o); s2 += __shfl_xor(s2, o); }
  if (lane == 0) { f1[i] = s1; f2[i] = s2; }
}

// ---------------- K2: h = xb @ WbT^T via MFMA bf16 (4 waves, 26 tiles) ------
__launch_bounds__(256)
__global__ void k_gemm(const u16* __restrict__ xb, const u16* __restrict__ WbT,
                       u16* __restrict__ hb){
  __shared__ __align__(16) u16 As[32 * 32];
  __shared__ __align__(16) u16 Bs[FP * 32];
  int tid = threadIdx.x, lane = tid & 63, wid = tid >> 6;
  int rb = blockIdx.x * 32;
  f32x4 acc[7];
  #pragma unroll
  for (int n = 0; n < 7; n++) acc[n] = (f32x4){0.f, 0.f, 0.f, 0.f};
  for (int k0 = 0; k0 < FIN; k0 += 32) {
    __syncthreads();
    if (tid < 128) {
      int r = tid >> 2, j = tid & 3;
      uint4 av = *(const uint4*)(xb + (size_t)(rb + r) * FIN + k0 + j * 8);
      *(uint4*)&As[r * 32 + (j ^ ((r >> 1) & 3)) * 8] = av;
    }
    for (int c = tid; c < FP * 4; c += 256) {
      int col = c >> 2, j = c & 3;
      uint4 bv = *(const uint4*)(WbT + (size_t)col * FIN + k0 + j * 8);
      *(uint4*)&Bs[col * 32 + (j ^ ((col >> 1) & 3)) * 8] = bv;
    }
    __syncthreads();
    int jr = lane >> 4;
    #pragma unroll
    for (int n = 0; n < 7; n++) {
      int t = wid + 4 * n;
      if (t < 26) {
        int rt = t / 13, ct = t % 13;
        int lr = rt * 16 + (lane & 15);
        short8 af = *(const short8*)&As[lr * 32 + (jr ^ ((lr >> 1) & 3)) * 8];
        int col = ct * 16 + (lane & 15);
        short8 bfv = *(const short8*)&Bs[col * 32 + (jr ^ ((col >> 1) & 3)) * 8];
        acc[n] = __builtin_amdgcn_mfma_f32_16x16x32_bf16(af, bfv, acc[n], 0, 0, 0);
      }
    }
  }
  #pragma unroll
  for (int n = 0; n < 7; n++) {
    int t = wid + 4 * n;
    if (t < 26) {
      int rt = t / 13, ct = t % 13;
      int rbase = rb + rt * 16 + 4 * (lane >> 4);
      int col = ct * 16 + (lane & 15);
      if (col < FO) {
        #pragma unroll
        for (int q = 0; q < 4; q++)
          hb[(size_t)(rbase + q) * FO + col] = f2bf(acc[n][q]);
      }
    }
  }
}

// ---------------- K3a: pure-stream scan+compact+softmax ---------------------
__launch_bounds__(256)
__global__ void k_scan(const float* __restrict__ support, const float* __restrict__ f1,
                       const float* __restrict__ f2, int* __restrict__ nnzg,
                       u16* __restrict__ idxg, float* __restrict__ valg,
                       float* __restrict__ attg){
  int i = blockIdx.x;
  int tid = threadIdx.x, lane = tid & 63, wid = tid >> 6;
  __shared__ u16 s_idx[CAP];
  __shared__ float s_val[CAP];
  __shared__ float s_red[8];
  __shared__ int s_base[4];
  const float4* row4 = (const float4*)(support + (size_t)i * NN);
  float4 v[8];
  #pragma unroll
  for (int k = 0; k < 8; k++) v[k] = row4[tid + 256 * k];
  int cnt = 0;
  #pragma unroll
  for (int k = 0; k < 8; k++)
    cnt += (v[k].x > 0.f) + (v[k].y > 0.f) + (v[k].z > 0.f) + (v[k].w > 0.f);
  int sc = cnt;
  #pragma unroll
  for (int o = 1; o < 64; o <<= 1) { int t2 = __shfl_up(sc, o); if (lane >= o) sc += t2; }
  if (lane == 63) s_base[wid] = sc;
  __syncthreads();
  int wbase = 0;
  for (int w = 0; w < wid; w++) wbase += s_base[w];
  int total = s_base[0] + s_base[1] + s_base[2] + s_base[3];
  int pos = wbase + sc - cnt;
  #pragma unroll
  for (int k = 0; k < 8; k++) {
    int cbase = (tid + 256 * k) * 4;
    if (v[k].x > 0.f && pos < CAP) { s_idx[pos] = (u16)(cbase + 0); s_val[pos] = v[k].x; pos++; }
    if (v[k].y > 0.f && pos < CAP) { s_idx[pos] = (u16)(cbase + 1); s_val[pos] = v[k].y; pos++; }
    if (v[k].z > 0.f && pos < CAP) { s_idx[pos] = (u16)(cbase + 2); s_val[pos] = v[k].z; pos++; }
    if (v[k].w > 0.f && pos < CAP) { s_idx[pos] = (u16)(cbase + 3); s_val[pos] = v[k].w; pos++; }
  }
  __syncthreads();
  int nnz = min(total, CAP);
  float fi = f1[i];
  float e = -1e30f;
  int j = 0;
  if (tid < nnz) {
    j = s_idx[tid];
    e = fi + f2[j];
    e = e > 0.f ? e : ALPHA * e;
  }
  float m = e;
  #pragma unroll
  for (int o = 32; o; o >>= 1) m = fmaxf(m, __shfl_xor(m, o));
  if (lane == 0) s_red[wid] = m;
  __syncthreads();
  m = fmaxf(fmaxf(s_red[0], s_red[1]), fmaxf(s_red[2], s_red[3]));
  float p = (tid < nnz) ? __expf(e - m) : 0.f;
  float s = p;
  #pragma unroll
  for (int o = 32; o; o >>= 1) s += __shfl_xor(s, o);
  if (lane == 0) s_red[4 + wid] = s;
  __syncthreads();
  float rs = 1.0f / (s_red[4] + s_red[5] + s_red[6] + s_red[7]);
  if (tid < nnz) {
    idxg[(size_t)i * CAP + tid] = (u16)j;
    valg[(size_t)i * CAP + tid] = s_val[tid];
    attg[(size_t)i * CAP + tid] = p * rs;
  }
  if (tid == 0) nnzg[i] = nnz;
}

// ---------------- K3b: h'[i] = elu( sum_j att_ij * h[j] ) -------------------
__launch_bounds__(128)
__global__ void k_gather(const int* __restrict__ nnzg, const u16* __restrict__ idxg,
                         const float* __restrict__ attg, const u16* __restrict__ hb,
                         float* __restrict__ hp){
  int i = blockIdx.x;
  int tid = threadIdx.x;
  __shared__ int s_j[CAP];
  __shared__ float s_w[CAP];
  int nnz = nnzg[i];
  for (int t = tid; t < nnz; t += 128) {
    s_j[t] = idxg[(size_t)i * CAP + t];
    s_w[t] = attg[(size_t)i * CAP + t];
  }
  __syncthreads();
  if (tid < 100) {
    float ax = 0.f, ay = 0.f;
    int jj = 0;
    for (; jj + 4 <= nnz; jj += 4) {
      #pragma unroll
      for (int q = 0; q < 4; q++) {
        int j = s_j[jj + q];
        float w = s_w[jj + q];
        u32 hv = *(const u32*)&hb[(size_t)j * FO + 2 * tid];
        ax = fmaf(w, bf2f((u16)(hv & 0xffffu)), ax);
        ay = fmaf(w, bf2f((u16)(hv >> 16)), ay);
      }
    }
    for (; jj < nnz; jj++) {
      int j = s_j[jj];
      float w = s_w[jj];
      u32 hv = *(const u32*)&hb[(size_t)j * FO + 2 * tid];
      ax = fmaf(w, bf2f((u16)(hv & 0xffffu)), ax);
      ay = fmaf(w, bf2f((u16)(hv >> 16)), ay);
    }
    float rx = ax > 0.f ? ax : expm1f(ax);
    float ry = ay > 0.f ? ay : expm1f(ay);
    *(float2*)&hp[(size_t)i * FO + 2 * tid] = make_float2(rx, ry);
  }
}

// ---------------- K4: g = h' @ W0 -------------------------------------------
__launch_bounds__(256)
__global__ void k_g(const float* __restrict__ hp, const float* __restrict__ W0,
                    float* __restrict__ g){
  __shared__ float w0s[FO * CO];
  for (int t = threadIdx.x; t < FO * CO; t += 256) w0s[t] = W0[t];
  __syncthreads();
  int t = threadIdx.x;
  if (t >= 240) return;
  int r = blockIdx.x * 12 + t / 20, c = t % 20;
  if (r >= NN) return;
  const float* hr = hp + (size_t)r * FO;
  float acc = 0.f;
  #pragma unroll 4
  for (int k = 0; k < FO; k++) acc = fmaf(hr[k], w0s[k * CO + c], acc);
  g[(size_t)r * CO + c] = acc;
}

// ---------------- K5: out = support @ g  (sparse rep, LDS-staged) ------------
__launch_bounds__(256)
__global__ void k_out(const int* __restrict__ nnzg, const u16* __restrict__ idxg,
                      const float* __restrict__ valg, const float* __restrict__ g,
                      float* __restrict__ out){
  int tid = threadIdx.x, lane = tid & 63, wid = tid >> 6;
  int i = blockIdx.x * 4 + wid;
  __shared__ int s_j[4][CAP];
  __shared__ float s_w[4][CAP];
  int nnz = nnzg[i];
  for (int t = lane; t < nnz; t += 64) {
    s_j[wid][t] = idxg[(size_t)i * CAP + t];
    s_w[wid][t] = valg[(size_t)i * CAP + t];
  }
  __syncthreads();
  int c = lane % 20, grp = lane / 20;
  float acc = 0.f;
  if (grp < 3) {
    for (int jj = grp; jj < nnz; jj += 3)
      acc = fmaf(s_w[wid][jj], g[(size_t)s_j[wid][jj] * CO + c], acc);
  }
  float b1 = __shfl(acc, lane + 20);
  float b2 = __shfl(acc, lane + 40);
  if (lane < 20) out[(size_t)i * CO + lane] = acc + b1 + b2;
}

extern "C" void kernel_launch(void* const* d_in, const int* in_sizes, int n_in,
                              void* d_out, int out_size, void* d_ws, size_t ws_size,
                              hipStream_t stream) {
  (void)in_sizes; (void)n_in; (void)out_size; (void)ws_size;
  const float* x       = (const float*)d_in[0];
  const float* support = (const float*)d_in[1];
  const float* W       = (const float*)d_in[2];
  const float* a1      = (const float*)d_in[3];
  const float* a2      = (const float*)d_in[4];
  const float* W0      = (const float*)d_in[5];
  char* ws = (char*)d_ws;
  u16*   xb   = (u16*)  (ws + 0);           // 8192*512*2      = 8388608
  u16*   WbT  = (u16*)  (ws + 8388608);     // 208*512*2       = 212992
  float* wa   = (float*)(ws + 8601600);     // 1024*4          = 4096
  float* f1   = (float*)(ws + 8605696);     // 8192*4          = 32768
  float* f2   = (float*)(ws + 8638464);     // 8192*4          = 32768
  u16*   hb   = (u16*)  (ws + 8671232);     // 8192*200*2      = 3276800
  float* hp   = (float*)(ws + 11948032);    // 8192*200*4      = 6553600
  float* g    = (float*)(ws + 18501632);    // 8192*20*4       = 655360
  int*   nnzg = (int*)  (ws + 19156992);    // 8192*4          = 32768
  u16*   idxg = (u16*)  (ws + 19189760);    // 8192*256*2      = 4194304
  float* valg = (float*)(ws + 23384064);    // 8192*256*4      = 8388608
  float* attg = (float*)(ws + 31772672);    // 8192*256*4      = 8388608
  float* outp = (float*)d_out;

  k_prep  <<<FP + 2,         256, 0, stream>>>(W, a1, a2, WbT, wa);
  k_xprep <<<NN / 4,         256, 0, stream>>>(x, wa, xb, f1, f2);
  k_gemm  <<<NN / 32,        256, 0, stream>>>(xb, WbT, hb);
  k_scan  <<<NN,             256, 0, stream>>>(support, f1, f2, nnzg, idxg, valg, attg);
  k_gather<<<NN,             128, 0, stream>>>(nnzg, idxg, attg, hb, hp);
  k_g     <<<(NN + 11) / 12, 256, 0, stream>>>(hp, W0, g);
  k_out   <<<NN / 4,         256, 0, stream>>>(nnzg, idxg, valg, g, outp);
}

// Round 3
// 132.830 us; speedup vs baseline: 1.3294x; 1.0842x over previous
//
#include <hip/hip_runtime.h>

typedef unsigned short u16;
typedef unsigned int u32;
typedef __attribute__((ext_vector_type(8))) short short8;
typedef __attribute__((ext_vector_type(4))) float f32x4;

#define NN 8192
#define FIN 512
#define FO 200
#define FP 208
#define CO 20
#define CAP 256
#define ALPHA 0.2f

__device__ __forceinline__ u16 f2bf(float f){
  union { float f; unsigned u; } c; c.f = f;
  unsigned u = c.u;
  return (u16)((u + 0x7fffu + ((u >> 16) & 1u)) >> 16);
}
__device__ __forceinline__ float bf2f(u16 s){
  union { unsigned u; float f; } c; c.u = ((unsigned)s) << 16;
  return c.f;
}

// ---------------- K0: WbT (bf16, padded transpose) + wa1/wa2 = W@a1, W@a2 ----
__global__ void k_prep(const float* __restrict__ W, const float* __restrict__ a1,
                       const float* __restrict__ a2, u16* __restrict__ WbT,
                       float* __restrict__ wa){
  __shared__ float al[FO];
  int b = blockIdx.x;
  if (b < FP) {
    int c = b;
    for (int k = threadIdx.x; k < FIN; k += 256) {
      float v = (c < FO) ? W[(size_t)k*FO + c] : 0.f;
      WbT[(size_t)c*FIN + k] = f2bf(v);
    }
  } else {
    const float* a = (b == FP) ? a1 : a2;
    float* out = wa + (size_t)(b - FP)*FIN;
    for (int t = threadIdx.x; t < FO; t += 256) al[t] = a[t];
    __syncthreads();
    for (int k = threadIdx.x; k < FIN; k += 256) {
      const float* wr = W + (size_t)k*FO;
      float acc = 0.f;
      for (int f = 0; f < FO; f++) acc = fmaf(wr[f], al[f], acc);
      out[k] = acc;
    }
  }
}

// ---------------- K1: xb = bf16(x); f1 = x@wa1; f2 = x@wa2 -------------------
__launch_bounds__(256)
__global__ void k_xprep(const float* __restrict__ x, const float* __restrict__ wa,
                        u16* __restrict__ xb, float* __restrict__ f1,
                        float* __restrict__ f2){
  int tid = threadIdx.x, lane = tid & 63, wid = tid >> 6;
  int i = blockIdx.x * 4 + wid;
  const f32x4* xr = (const f32x4*)(x + (size_t)i * FIN);
  f32x4 xa = __builtin_nontemporal_load(&xr[lane]);
  f32x4 xc = __builtin_nontemporal_load(&xr[lane + 64]);
  ushort4 pa, pb;
  pa.x = f2bf(xa[0]); pa.y = f2bf(xa[1]); pa.z = f2bf(xa[2]); pa.w = f2bf(xa[3]);
  pb.x = f2bf(xc[0]); pb.y = f2bf(xc[1]); pb.z = f2bf(xc[2]); pb.w = f2bf(xc[3]);
  ushort4* xbo = (ushort4*)(xb + (size_t)i * FIN);
  xbo[lane] = pa; xbo[lane + 64] = pb;
  const f32x4* w1 = (const f32x4*)wa;
  const f32x4* w2 = (const f32x4*)(wa + FIN);
  f32x4 w1a = w1[lane], w1b = w1[lane + 64];
  f32x4 w2a = w2[lane], w2b = w2[lane + 64];
  float s1 = xa[0]*w1a[0] + xa[1]*w1a[1] + xa[2]*w1a[2] + xa[3]*w1a[3]
           + xc[0]*w1b[0] + xc[1]*w1b[1] + xc[2]*w1b[2] + xc[3]*w1b[3];
  float s2 = xa[0]*w2a[0] + xa[1]*w2a[1] + xa[2]*w2a[2] + xa[3]*w2a[3]
           + xc[0]*w2b[0] + xc[1]*w2b[1] + xc[2]*w2b[2] + xc[3]*w2b[3];
  #pragma unroll
  for (int o = 32; o; o >>= 1) { s1 += __shfl_xor(s1, o); s2 += __shfl_xor(s2, o); }
  if (lane == 0) { f1[i] = s1; f2[i] = s2; }
}

// ---------------- K2: h = xb @ WbT^T via MFMA bf16 (4 waves, 26 tiles) ------
__launch_bounds__(256)
__global__ void k_gemm(const u16* __restrict__ xb, const u16* __restrict__ WbT,
                       u16* __restrict__ hb){
  __shared__ __align__(16) u16 As[32 * 32];
  __shared__ __align__(16) u16 Bs[FP * 32];
  int tid = threadIdx.x, lane = tid & 63, wid = tid >> 6;
  int rb = blockIdx.x * 32;
  f32x4 acc[7];
  #pragma unroll
  for (int n = 0; n < 7; n++) acc[n] = (f32x4){0.f, 0.f, 0.f, 0.f};
  for (int k0 = 0; k0 < FIN; k0 += 32) {
    __syncthreads();
    if (tid < 128) {
      int r = tid >> 2, j = tid & 3;
      uint4 av = *(const uint4*)(xb + (size_t)(rb + r) * FIN + k0 + j * 8);
      *(uint4*)&As[r * 32 + (j ^ ((r >> 1) & 3)) * 8] = av;
    }
    for (int c = tid; c < FP * 4; c += 256) {
      int col = c >> 2, j = c & 3;
      uint4 bv = *(const uint4*)(WbT + (size_t)col * FIN + k0 + j * 8);
      *(uint4*)&Bs[col * 32 + (j ^ ((col >> 1) & 3)) * 8] = bv;
    }
    __syncthreads();
    int jr = lane >> 4;
    #pragma unroll
    for (int n = 0; n < 7; n++) {
      int t = wid + 4 * n;
      if (t < 26) {
        int rt = t / 13, ct = t % 13;
        int lr = rt * 16 + (lane & 15);
        short8 af = *(const short8*)&As[lr * 32 + (jr ^ ((lr >> 1) & 3)) * 8];
        int col = ct * 16 + (lane & 15);
        short8 bfv = *(const short8*)&Bs[col * 32 + (jr ^ ((col >> 1) & 3)) * 8];
        acc[n] = __builtin_amdgcn_mfma_f32_16x16x32_bf16(af, bfv, acc[n], 0, 0, 0);
      }
    }
  }
  #pragma unroll
  for (int n = 0; n < 7; n++) {
    int t = wid + 4 * n;
    if (t < 26) {
      int rt = t / 13, ct = t % 13;
      int rbase = rb + rt * 16 + 4 * (lane >> 4);
      int col = ct * 16 + (lane & 15);
      if (col < FO) {
        #pragma unroll
        for (int q = 0; q < 4; q++)
          hb[(size_t)(rbase + q) * FO + col] = f2bf(acc[n][q]);
      }
    }
  }
}

// ---------------- K3: pure-stream compact (no softmax, no LDS staging) ------
__launch_bounds__(256)
__global__ void k_compact(const float* __restrict__ support, int* __restrict__ nnzg,
                          u16* __restrict__ idxg, float* __restrict__ valg){
  int i = blockIdx.x;
  int tid = threadIdx.x, lane = tid & 63, wid = tid >> 6;
  __shared__ int s_base[4];
  const f32x4* row4 = (const f32x4*)(support + (size_t)i * NN);
  f32x4 v[8];
  #pragma unroll
  for (int k = 0; k < 8; k++) v[k] = __builtin_nontemporal_load(&row4[tid + 256 * k]);
  int cnt = 0;
  #pragma unroll
  for (int k = 0; k < 8; k++)
    cnt += (v[k][0] > 0.f) + (v[k][1] > 0.f) + (v[k][2] > 0.f) + (v[k][3] > 0.f);
  int sc = cnt;
  #pragma unroll
  for (int o = 1; o < 64; o <<= 1) { int t2 = __shfl_up(sc, o); if (lane >= o) sc += t2; }
  if (lane == 63) s_base[wid] = sc;
  __syncthreads();
  int wbase = 0;
  for (int w = 0; w < wid; w++) wbase += s_base[w];
  int total = s_base[0] + s_base[1] + s_base[2] + s_base[3];
  int pos = wbase + sc - cnt;
  u16* ig = idxg + (size_t)i * CAP;
  float* vg = valg + (size_t)i * CAP;
  #pragma unroll
  for (int k = 0; k < 8; k++) {
    int cbase = (tid + 256 * k) * 4;
    #pragma unroll
    for (int c = 0; c < 4; c++) {
      if (v[k][c] > 0.f && pos < CAP) {
        ig[pos] = (u16)(cbase + c);
        vg[pos] = v[k][c];
        pos++;
      }
    }
  }
  if (tid == 0) nnzg[i] = min(total, CAP);
}

// ---------------- K4: softmax + h'=elu(att@h) + g = h'@W0 (fused) -----------
__launch_bounds__(128)
__global__ void k_gather(const int* __restrict__ nnzg, const u16* __restrict__ idxg,
                         const float* __restrict__ f1, const float* __restrict__ f2,
                         const u16* __restrict__ hb, const float* __restrict__ W0,
                         float* __restrict__ g){
  int i = blockIdx.x;
  int tid = threadIdx.x, lane = tid & 63, wid = tid >> 6;
  __shared__ int s_j[CAP];
  __shared__ float s_w[CAP];
  __shared__ float s_red[4];
  __shared__ float s_hp[FO];
  __shared__ float s_part[120];
  int nnz = nnzg[i];
  for (int t = tid; t < nnz; t += 128) s_j[t] = idxg[(size_t)i * CAP + t];
  __syncthreads();
  float fi = f1[i];
  float e0 = -1e30f, e1 = -1e30f;
  if (tid < nnz)       { float e = fi + f2[s_j[tid]];       e0 = e > 0.f ? e : ALPHA * e; }
  if (tid + 128 < nnz) { float e = fi + f2[s_j[tid + 128]]; e1 = e > 0.f ? e : ALPHA * e; }
  float m = fmaxf(e0, e1);
  #pragma unroll
  for (int o = 32; o; o >>= 1) m = fmaxf(m, __shfl_xor(m, o));
  if (lane == 0) s_red[wid] = m;
  __syncthreads();
  m = fmaxf(s_red[0], s_red[1]);
  float p0 = (tid < nnz)       ? __expf(e0 - m) : 0.f;
  float p1 = (tid + 128 < nnz) ? __expf(e1 - m) : 0.f;
  float s = p0 + p1;
  #pragma unroll
  for (int o = 32; o; o >>= 1) s += __shfl_xor(s, o);
  if (lane == 0) s_red[2 + wid] = s;
  __syncthreads();
  float rs = 1.0f / (s_red[2] + s_red[3]);
  if (tid < nnz)       s_w[tid]       = p0 * rs;
  if (tid + 128 < nnz) s_w[tid + 128] = p1 * rs;
  __syncthreads();
  if (tid < 100) {
    float ax = 0.f, ay = 0.f;
    int jj = 0;
    for (; jj + 8 <= nnz; jj += 8) {
      #pragma unroll
      for (int q = 0; q < 8; q++) {
        int j = s_j[jj + q];
        float w = s_w[jj + q];
        u32 hv = *(const u32*)&hb[(size_t)j * FO + 2 * tid];
        ax = fmaf(w, bf2f((u16)(hv & 0xffffu)), ax);
        ay = fmaf(w, bf2f((u16)(hv >> 16)), ay);
      }
    }
    for (; jj < nnz; jj++) {
      int j = s_j[jj];
      float w = s_w[jj];
      u32 hv = *(const u32*)&hb[(size_t)j * FO + 2 * tid];
      ax = fmaf(w, bf2f((u16)(hv & 0xffffu)), ax);
      ay = fmaf(w, bf2f((u16)(hv >> 16)), ay);
    }
    s_hp[2 * tid]     = ax > 0.f ? ax : expm1f(ax);
    s_hp[2 * tid + 1] = ay > 0.f ? ay : expm1f(ay);
  }
  __syncthreads();
  if (tid < 120) {
    int c = tid % 20, dg = tid / 20;
    float acc = 0.f;
    for (int d = dg; d < FO; d += 6)
      acc = fmaf(s_hp[d], W0[d * CO + c], acc);
    s_part[tid] = acc;
  }
  __syncthreads();
  if (tid < 20) {
    float a = s_part[tid] + s_part[tid + 20] + s_part[tid + 40]
            + s_part[tid + 60] + s_part[tid + 80] + s_part[tid + 100];
    g[(size_t)i * CO + tid] = a;
  }
}

// ---------------- K5: out = support @ g  (sparse rep, LDS-staged) ------------
__launch_bounds__(256)
__global__ void k_out(const int* __restrict__ nnzg, const u16* __restrict__ idxg,
                      const float* __restrict__ valg, const float* __restrict__ g,
                      float* __restrict__ out){
  int tid = threadIdx.x, lane = tid & 63, wid = tid >> 6;
  int i = blockIdx.x * 4 + wid;
  __shared__ int s_j[4][CAP];
  __shared__ float s_w[4][CAP];
  int nnz = nnzg[i];
  for (int t = lane; t < nnz; t += 64) {
    s_j[wid][t] = idxg[(size_t)i * CAP + t];
    s_w[wid][t] = valg[(size_t)i * CAP + t];
  }
  __syncthreads();
  int c = lane % 20, grp = lane / 20;
  float acc = 0.f;
  if (grp < 3) {
    for (int jj = grp; jj < nnz; jj += 3)
      acc = fmaf(s_w[wid][jj], g[(size_t)s_j[wid][jj] * CO + c], acc);
  }
  float b1 = __shfl(acc, lane + 20);
  float b2 = __shfl(acc, lane + 40);
  if (lane < 20) out[(size_t)i * CO + lane] = acc + b1 + b2;
}

extern "C" void kernel_launch(void* const* d_in, const int* in_sizes, int n_in,
                              void* d_out, int out_size, void* d_ws, size_t ws_size,
                              hipStream_t stream) {
  (void)in_sizes; (void)n_in; (void)out_size; (void)ws_size;
  const float* x       = (const float*)d_in[0];
  const float* support = (const float*)d_in[1];
  const float* W       = (const float*)d_in[2];
  const float* a1      = (const float*)d_in[3];
  const float* a2      = (const float*)d_in[4];
  const float* W0      = (const float*)d_in[5];
  char* ws = (char*)d_ws;
  u16*   xb   = (u16*)  (ws + 0);           // 8192*512*2      = 8388608
  u16*   WbT  = (u16*)  (ws + 8388608);     // 208*512*2       = 212992
  float* wa   = (float*)(ws + 8601600);     // 1024*4          = 4096
  float* f1   = (float*)(ws + 8605696);     // 8192*4          = 32768
  float* f2   = (float*)(ws + 8638464);     // 8192*4          = 32768
  u16*   hb   = (u16*)  (ws + 8671232);     // 8192*200*2      = 3276800
  float* g    = (float*)(ws + 11948032);    // 8192*20*4       = 655360
  int*   nnzg = (int*)  (ws + 12603392);    // 8192*4          = 32768
  u16*   idxg = (u16*)  (ws + 12636160);    // 8192*256*2      = 4194304
  float* valg = (float*)(ws + 16830464);    // 8192*256*4      = 8388608
  float* outp = (float*)d_out;

  k_prep   <<<FP + 2, 256, 0, stream>>>(W, a1, a2, WbT, wa);
  k_xprep  <<<NN / 4, 256, 0, stream>>>(x, wa, xb, f1, f2);
  k_gemm   <<<NN / 32, 256, 0, stream>>>(xb, WbT, hb);
  k_compact<<<NN, 256, 0, stream>>>(support, nnzg, idxg, valg);
  k_gather <<<NN, 128, 0, stream>>>(nnzg, idxg, f1, f2, hb, W0, g);
  k_out    <<<NN / 4, 256, 0, stream>>>(nnzg, idxg, valg, g, outp);
}

// Round 4
// 128.052 us; speedup vs baseline: 1.3790x; 1.0373x over previous
//
#include <hip/hip_runtime.h>

typedef unsigned short u16;
typedef unsigned int u32;
typedef __attribute__((ext_vector_type(8))) short short8;
typedef __attribute__((ext_vector_type(4))) float f32x4;

#define NN 8192
#define FIN 512
#define FO 200
#define FP 208
#define CO 20
#define CAP 256
#define ALPHA 0.2f

__device__ __forceinline__ u16 f2bf(float f){
  union { float f; unsigned u; } c; c.f = f;
  unsigned u = c.u;
  return (u16)((u + 0x7fffu + ((u >> 16) & 1u)) >> 16);
}
__device__ __forceinline__ float bf2f(u16 s){
  union { unsigned u; float f; } c; c.u = ((unsigned)s) << 16;
  return c.f;
}

// ---------------- K0: WbT = bf16(W^T) padded to 208 cols --------------------
__global__ void k_prep(const float* __restrict__ W, u16* __restrict__ WbT){
  int c = blockIdx.x;
  for (int k = threadIdx.x; k < FIN; k += 256) {
    float v = (c < FO) ? W[(size_t)k*FO + c] : 0.f;
    WbT[(size_t)c*FIN + k] = f2bf(v);
  }
}

// ---------------- K1 fused: [0,NN) compact-stream | [NN,NN+256) gemm --------
__launch_bounds__(256)
__global__ void k_main(const float* __restrict__ support, const float* __restrict__ x,
                       const u16* __restrict__ WbT, const float* __restrict__ a1,
                       const float* __restrict__ a2, u16* __restrict__ hb,
                       float* __restrict__ f1, float* __restrict__ f2,
                       int* __restrict__ nnzg, u16* __restrict__ idxg,
                       float* __restrict__ valg){
  int tid = threadIdx.x, lane = tid & 63, wid = tid >> 6;
  if (blockIdx.x < NN) {
    // ======== compact role: stream one support row, emit (idx,val) ========
    int i = blockIdx.x;
    __shared__ int s_base[4];
    const f32x4* row4 = (const f32x4*)(support + (size_t)i * NN);
    f32x4 v[8];
    #pragma unroll
    for (int k = 0; k < 8; k++) v[k] = __builtin_nontemporal_load(&row4[tid + 256 * k]);
    int cnt = 0;
    #pragma unroll
    for (int k = 0; k < 8; k++)
      cnt += (v[k][0] > 0.f) + (v[k][1] > 0.f) + (v[k][2] > 0.f) + (v[k][3] > 0.f);
    int sc = cnt;
    #pragma unroll
    for (int o = 1; o < 64; o <<= 1) { int t2 = __shfl_up(sc, o); if (lane >= o) sc += t2; }
    if (lane == 63) s_base[wid] = sc;
    __syncthreads();
    int wbase = 0;
    for (int w = 0; w < wid; w++) wbase += s_base[w];
    int total = s_base[0] + s_base[1] + s_base[2] + s_base[3];
    int pos = wbase + sc - cnt;
    u16* ig = idxg + (size_t)i * CAP;
    float* vg = valg + (size_t)i * CAP;
    #pragma unroll
    for (int k = 0; k < 8; k++) {
      int cbase = (tid + 256 * k) * 4;
      #pragma unroll
      for (int c = 0; c < 4; c++) {
        if (v[k][c] > 0.f && pos < CAP) {
          ig[pos] = (u16)(cbase + c);
          vg[pos] = v[k][c];
          pos++;
        }
      }
    }
    if (tid == 0) nnzg[i] = min(total, CAP);
    return;
  }
  // ======== gemm role: h = bf16(x) @ WbT^T, + f1 = h@a1, f2 = h@a2 ========
  int bi = blockIdx.x - NN;
  int rb = bi * 32;
  __shared__ __align__(16) u16 As[32 * 32];
  __shared__ __align__(16) u16 Bs[FP * 32];
  __shared__ float a1s[FP], a2s[FP];
  __shared__ float fpart[2][4][32];
  if (tid < FP) {
    a1s[tid] = (tid < FO) ? a1[tid] : 0.f;
    a2s[tid] = (tid < FO) ? a2[tid] : 0.f;
  }
  f32x4 acc[7];
  #pragma unroll
  for (int n = 0; n < 7; n++) acc[n] = (f32x4){0.f, 0.f, 0.f, 0.f};
  for (int k0 = 0; k0 < FIN; k0 += 32) {
    __syncthreads();
    {
      int r = tid >> 3, kk = (tid & 7) * 4;
      const f32x4* xp = (const f32x4*)(x + (size_t)(rb + r) * FIN + k0 + kk);
      f32x4 xv = __builtin_nontemporal_load(xp);
      ushort4 hv;
      hv.x = f2bf(xv[0]); hv.y = f2bf(xv[1]); hv.z = f2bf(xv[2]); hv.w = f2bf(xv[3]);
      *(ushort4*)&As[r * 32 + (((kk >> 3) ^ ((r >> 1) & 3)) * 8) + (kk & 7)] = hv;
    }
    for (int c = tid; c < FP * 4; c += 256) {
      int col = c >> 2, j = c & 3;
      uint4 bv = *(const uint4*)(WbT + (size_t)col * FIN + k0 + j * 8);
      *(uint4*)&Bs[col * 32 + (j ^ ((col >> 1) & 3)) * 8] = bv;
    }
    __syncthreads();
    int jr = lane >> 4;
    #pragma unroll
    for (int n = 0; n < 7; n++) {
      int t = wid + 4 * n;
      if (t < 26) {
        int rt = t / 13, ct = t % 13;
        int lr = rt * 16 + (lane & 15);
        short8 af = *(const short8*)&As[lr * 32 + (jr ^ ((lr >> 1) & 3)) * 8];
        int col = ct * 16 + (lane & 15);
        short8 bfv = *(const short8*)&Bs[col * 32 + (jr ^ ((col >> 1) & 3)) * 8];
        acc[n] = __builtin_amdgcn_mfma_f32_16x16x32_bf16(af, bfv, acc[n], 0, 0, 0);
      }
    }
  }
  // epilogue: write hb (bf16) + accumulate f1/f2 partials in f32
  float f1a[2][4] = {{0.f,0.f,0.f,0.f},{0.f,0.f,0.f,0.f}};
  float f2a[2][4] = {{0.f,0.f,0.f,0.f},{0.f,0.f,0.f,0.f}};
  #pragma unroll
  for (int n = 0; n < 7; n++) {
    int t = wid + 4 * n;
    if (t < 26) {
      int rt = t / 13, ct = t % 13;
      int col = ct * 16 + (lane & 15);
      float av1 = a1s[col], av2 = a2s[col];
      int rbase = rb + rt * 16 + 4 * (lane >> 4);
      #pragma unroll
      for (int q = 0; q < 4; q++) {
        float hv = acc[n][q];
        if (col < FO) hb[(size_t)(rbase + q) * FO + col] = f2bf(hv);
        f1a[rt][q] = fmaf(hv, av1, f1a[rt][q]);
        f2a[rt][q] = fmaf(hv, av2, f2a[rt][q]);
      }
    }
  }
  #pragma unroll
  for (int rt = 0; rt < 2; rt++) {
    #pragma unroll
    for (int q = 0; q < 4; q++) {
      float v1 = f1a[rt][q], v2 = f2a[rt][q];
      #pragma unroll
      for (int o = 1; o < 16; o <<= 1) { v1 += __shfl_xor(v1, o); v2 += __shfl_xor(v2, o); }
      if ((lane & 15) == 0) {
        int row = rt * 16 + 4 * (lane >> 4) + q;
        fpart[0][wid][row] = v1;
        fpart[1][wid][row] = v2;
      }
    }
  }
  __syncthreads();
  if (tid < 32) {
    f1[rb + tid] = fpart[0][0][tid] + fpart[0][1][tid] + fpart[0][2][tid] + fpart[0][3][tid];
    f2[rb + tid] = fpart[1][0][tid] + fpart[1][1][tid] + fpart[1][2][tid] + fpart[1][3][tid];
  }
}

// ---------------- K2: softmax + h'=elu(att@h) + g = h'@W0 (fused) -----------
__launch_bounds__(128)
__global__ void k_gather(const int* __restrict__ nnzg, const u16* __restrict__ idxg,
                         const float* __restrict__ f1, const float* __restrict__ f2,
                         const u16* __restrict__ hb, const float* __restrict__ W0,
                         float* __restrict__ g){
  int i = blockIdx.x;
  int tid = threadIdx.x, lane = tid & 63, wid = tid >> 6;
  __shared__ int s_j[CAP];
  __shared__ float s_w[CAP];
  __shared__ float s_red[4];
  __shared__ float s_hp[FO];
  __shared__ float s_part[120];
  int nnz = nnzg[i];
  for (int t = tid; t < nnz; t += 128) s_j[t] = idxg[(size_t)i * CAP + t];
  __syncthreads();
  float fi = f1[i];
  float e0 = -1e30f, e1 = -1e30f;
  if (tid < nnz)       { float e = fi + f2[s_j[tid]];       e0 = e > 0.f ? e : ALPHA * e; }
  if (tid + 128 < nnz) { float e = fi + f2[s_j[tid + 128]]; e1 = e > 0.f ? e : ALPHA * e; }
  float m = fmaxf(e0, e1);
  #pragma unroll
  for (int o = 32; o; o >>= 1) m = fmaxf(m, __shfl_xor(m, o));
  if (lane == 0) s_red[wid] = m;
  __syncthreads();
  m = fmaxf(s_red[0], s_red[1]);
  float p0 = (tid < nnz)       ? __expf(e0 - m) : 0.f;
  float p1 = (tid + 128 < nnz) ? __expf(e1 - m) : 0.f;
  float s = p0 + p1;
  #pragma unroll
  for (int o = 32; o; o >>= 1) s += __shfl_xor(s, o);
  if (lane == 0) s_red[2 + wid] = s;
  __syncthreads();
  float rs = 1.0f / (s_red[2] + s_red[3]);
  if (tid < nnz)       s_w[tid]       = p0 * rs;
  if (tid + 128 < nnz) s_w[tid + 128] = p1 * rs;
  __syncthreads();
  if (tid < 100) {
    float ax = 0.f, ay = 0.f;
    int jj = 0;
    for (; jj + 8 <= nnz; jj += 8) {
      #pragma unroll
      for (int q = 0; q < 8; q++) {
        int j = s_j[jj + q];
        float w = s_w[jj + q];
        u32 hv = *(const u32*)&hb[(size_t)j * FO + 2 * tid];
        ax = fmaf(w, bf2f((u16)(hv & 0xffffu)), ax);
        ay = fmaf(w, bf2f((u16)(hv >> 16)), ay);
      }
    }
    for (; jj < nnz; jj++) {
      int j = s_j[jj];
      float w = s_w[jj];
      u32 hv = *(const u32*)&hb[(size_t)j * FO + 2 * tid];
      ax = fmaf(w, bf2f((u16)(hv & 0xffffu)), ax);
      ay = fmaf(w, bf2f((u16)(hv >> 16)), ay);
    }
    s_hp[2 * tid]     = ax > 0.f ? ax : expm1f(ax);
    s_hp[2 * tid + 1] = ay > 0.f ? ay : expm1f(ay);
  }
  __syncthreads();
  if (tid < 120) {
    int c = tid % 20, dg = tid / 20;
    float acc = 0.f;
    for (int d = dg; d < FO; d += 6)
      acc = fmaf(s_hp[d], W0[d * CO + c], acc);
    s_part[tid] = acc;
  }
  __syncthreads();
  if (tid < 20) {
    float a = s_part[tid] + s_part[tid + 20] + s_part[tid + 40]
            + s_part[tid + 60] + s_part[tid + 80] + s_part[tid + 100];
    g[(size_t)i * CO + tid] = a;
  }
}

// ---------------- K3: out = support @ g  (sparse rep, LDS-staged) ------------
__launch_bounds__(256)
__global__ void k_out(const int* __restrict__ nnzg, const u16* __restrict__ idxg,
                      const float* __restrict__ valg, const float* __restrict__ g,
                      float* __restrict__ out){
  int tid = threadIdx.x, lane = tid & 63, wid = tid >> 6;
  int i = blockIdx.x * 4 + wid;
  __shared__ int s_j[4][CAP];
  __shared__ float s_w[4][CAP];
  int nnz = nnzg[i];
  for (int t = lane; t < nnz; t += 64) {
    s_j[wid][t] = idxg[(size_t)i * CAP + t];
    s_w[wid][t] = valg[(size_t)i * CAP + t];
  }
  __syncthreads();
  int c = lane % 20, grp = lane / 20;
  float acc = 0.f;
  if (grp < 3) {
    for (int jj = grp; jj < nnz; jj += 3)
      acc = fmaf(s_w[wid][jj], g[(size_t)s_j[wid][jj] * CO + c], acc);
  }
  float b1 = __shfl(acc, lane + 20);
  float b2 = __shfl(acc, lane + 40);
  if (lane < 20) out[(size_t)i * CO + lane] = acc + b1 + b2;
}

extern "C" void kernel_launch(void* const* d_in, const int* in_sizes, int n_in,
                              void* d_out, int out_size, void* d_ws, size_t ws_size,
                              hipStream_t stream) {
  (void)in_sizes; (void)n_in; (void)out_size; (void)ws_size;
  const float* x       = (const float*)d_in[0];
  const float* support = (const float*)d_in[1];
  const float* W       = (const float*)d_in[2];
  const float* a1      = (const float*)d_in[3];
  const float* a2      = (const float*)d_in[4];
  const float* W0      = (const float*)d_in[5];
  char* ws = (char*)d_ws;
  u16*   WbT  = (u16*)  (ws + 0);          // 208*512*2   = 212992
  float* f1   = (float*)(ws + 212992);     // 8192*4      = 32768
  float* f2   = (float*)(ws + 245760);     // 8192*4      = 32768
  u16*   hb   = (u16*)  (ws + 278528);     // 8192*200*2  = 3276800
  float* g    = (float*)(ws + 3555328);    // 8192*20*4   = 655360
  int*   nnzg = (int*)  (ws + 4210688);    // 8192*4      = 32768
  u16*   idxg = (u16*)  (ws + 4243456);    // 8192*256*2  = 4194304
  float* valg = (float*)(ws + 8437760);    // 8192*256*4  = 8388608
  float* outp = (float*)d_out;

  k_prep  <<<FP,       256, 0, stream>>>(W, WbT);
  k_main  <<<NN + 256, 256, 0, stream>>>(support, x, WbT, a1, a2, hb, f1, f2, nnzg, idxg, valg);
  k_gather<<<NN,       128, 0, stream>>>(nnzg, idxg, f1, f2, hb, W0, g);
  k_out   <<<NN / 4,   256, 0, stream>>>(nnzg, idxg, valg, g, outp);
}

// Round 6
// 124.186 us; speedup vs baseline: 1.4219x; 1.0311x over previous
//
#include <hip/hip_runtime.h>

typedef unsigned short u16;
typedef unsigned int u32;
typedef unsigned long long u64;
typedef __attribute__((ext_vector_type(8))) short short8;
typedef __attribute__((ext_vector_type(4))) float f32x4;

#define NN 8192
#define FIN 512
#define FO 200
#define FP 208
#define CO 20
#define CAP 256
#define ALPHA 0.2f
#define GEMM_BLOCKS 256
#define COMPACT_BLOCKS 2048

__device__ __forceinline__ u16 f2bf(float f){
  union { float f; unsigned u; } c; c.f = f;
  unsigned u = c.u;
  return (u16)((u + 0x7fffu + ((u >> 16) & 1u)) >> 16);
}
__device__ __forceinline__ float bf2f(u16 s){
  union { unsigned u; float f; } c; c.u = ((unsigned)s) << 16;
  return c.f;
}

// =================== K1 fused: [0,256) gemm | [256,2304) compact ============
__launch_bounds__(256)
__global__ void k_main(const float* __restrict__ support, const float* __restrict__ x,
                       const float* __restrict__ W, const float* __restrict__ a1,
                       const float* __restrict__ a2, u16* __restrict__ hb,
                       float* __restrict__ f1, float* __restrict__ f2,
                       int* __restrict__ nnzg, u16* __restrict__ idxg,
                       float* __restrict__ valg){
  int tid = threadIdx.x, lane = tid & 63, wid = tid >> 6;
  int bid = blockIdx.x;

  if (bid >= GEMM_BLOCKS) {
    // ======== compact role: one row PER WAVE, no __syncthreads ========
    int i = (bid - GEMM_BLOCKS) * 4 + wid;
    const f32x4* row4 = (const f32x4*)(support + (size_t)i * NN);
    u16* ig = idxg + (size_t)i * CAP;
    float* vg = valg + (size_t)i * CAP;
    u64 lanemask = (1ull << lane) - 1ull;
    int base = 0;
    f32x4 bufA[8], bufB[8];
#define LOAD_GROUP(buf, g) { \
    _Pragma("unroll") \
    for (int k = 0; k < 8; k++) buf[k] = row4[(g) * 512 + k * 64 + lane]; }
#define PROC_GROUP(buf, g) { \
    _Pragma("unroll") \
    for (int k = 0; k < 8; k++) { \
      _Pragma("unroll") \
      for (int c = 0; c < 4; c++) { \
        float val = buf[k][c]; \
        bool p = val > 0.f; \
        u64 mk = __ballot(p); \
        if (p) { \
          int pos = base + __popcll(mk & lanemask); \
          if (pos < CAP) { \
            ig[pos] = (u16)((g) * 2048 + (k * 64 + lane) * 4 + c); \
            vg[pos] = val; \
          } \
        } \
        base += __popcll(mk); \
      } } }
    LOAD_GROUP(bufA, 0)
    LOAD_GROUP(bufB, 1)
    PROC_GROUP(bufA, 0)
    LOAD_GROUP(bufA, 2)
    PROC_GROUP(bufB, 1)
    LOAD_GROUP(bufB, 3)
    PROC_GROUP(bufA, 2)
    PROC_GROUP(bufB, 3)
#undef LOAD_GROUP
#undef PROC_GROUP
    if (lane == 0) nnzg[i] = min(base, CAP);
    return;
  }

  // ======== gemm role: h = bf16(x) @ bf16(W), f1/f2 epilogue ========
  __shared__ __align__(16) u16 As[32 * 32];
  __shared__ __align__(16) u16 Bs[FP * 32];
  __shared__ float a1s[FP], a2s[FP];
  __shared__ float fpart[2][4][32];
  int rb = bid * 32;
  if (tid < FP) {
    a1s[tid] = (tid < FO) ? a1[tid] : 0.f;
    a2s[tid] = (tid < FO) ? a2[tid] : 0.f;
  }
  // zero the pad cols (200..207) of Bs once; never rewritten
  if (tid < 256) Bs[(200 + (tid >> 5)) * 32 + (tid & 31)] = 0;
  int r2 = 0, c4 = 0;
  if (tid < 200) { r2 = tid / 50; c4 = tid % 50; }
  f32x4 acc[7];
  #pragma unroll
  for (int n = 0; n < 7; n++) acc[n] = (f32x4){0.f, 0.f, 0.f, 0.f};
  for (int k0 = 0; k0 < FIN; k0 += 32) {
    __syncthreads();
    {
      int r = tid >> 3, kk = (tid & 7) * 4;
      const f32x4* xp = (const f32x4*)(x + (size_t)(rb + r) * FIN + k0 + kk);
      f32x4 xv = *xp;
      ushort4 hv;
      hv.x = f2bf(xv[0]); hv.y = f2bf(xv[1]); hv.z = f2bf(xv[2]); hv.w = f2bf(xv[3]);
      *(ushort4*)&As[r * 32 + (((kk >> 3) ^ ((r >> 1) & 3)) * 8) + (kk & 7)] = hv;
    }
    if (tid < 200) {
      #pragma unroll
      for (int g2 = 0; g2 < 8; g2++) {
        int row = g2 * 4 + r2;
        f32x4 wv = *(const f32x4*)(W + (size_t)(k0 + row) * FO + c4 * 4);
        int grp = (row >> 3), within = (row & 7);
        #pragma unroll
        for (int j = 0; j < 4; j++) {
          int col = c4 * 4 + j;
          Bs[col * 32 + ((grp ^ ((col >> 1) & 3)) * 8) + within] = f2bf(wv[j]);
        }
      }
    }
    __syncthreads();
    int jr = lane >> 4;
    #pragma unroll
    for (int n = 0; n < 7; n++) {
      int t = wid + 4 * n;
      if (t < 26) {
        int rt = t / 13, ct = t % 13;
        int lr = rt * 16 + (lane & 15);
        short8 af = *(const short8*)&As[lr * 32 + (jr ^ ((lr >> 1) & 3)) * 8];
        int col = ct * 16 + (lane & 15);
        short8 bfv = *(const short8*)&Bs[col * 32 + (jr ^ ((col >> 1) & 3)) * 8];
        acc[n] = __builtin_amdgcn_mfma_f32_16x16x32_bf16(af, bfv, acc[n], 0, 0, 0);
      }
    }
  }
  float f1a[2][4] = {{0.f,0.f,0.f,0.f},{0.f,0.f,0.f,0.f}};
  float f2a[2][4] = {{0.f,0.f,0.f,0.f},{0.f,0.f,0.f,0.f}};
  #pragma unroll
  for (int n = 0; n < 7; n++) {
    int t = wid + 4 * n;
    if (t < 26) {
      int rt = t / 13, ct = t % 13;
      int col = ct * 16 + (lane & 15);
      float av1 = a1s[col], av2 = a2s[col];
      int rbase = rb + rt * 16 + 4 * (lane >> 4);
      #pragma unroll
      for (int q = 0; q < 4; q++) {
        float hv = acc[n][q];
        if (col < FO) hb[(size_t)(rbase + q) * FO + col] = f2bf(hv);
        f1a[rt][q] = fmaf(hv, av1, f1a[rt][q]);
        f2a[rt][q] = fmaf(hv, av2, f2a[rt][q]);
      }
    }
  }
  #pragma unroll
  for (int rt = 0; rt < 2; rt++) {
    #pragma unroll
    for (int q = 0; q < 4; q++) {
      float v1 = f1a[rt][q], v2 = f2a[rt][q];
      #pragma unroll
      for (int o = 1; o < 16; o <<= 1) { v1 += __shfl_xor(v1, o); v2 += __shfl_xor(v2, o); }
      if ((lane & 15) == 0) {
        int row = rt * 16 + 4 * (lane >> 4) + q;
        fpart[0][wid][row] = v1;
        fpart[1][wid][row] = v2;
      }
    }
  }
  __syncthreads();
  if (tid < 32) {
    f1[rb + tid] = fpart[0][0][tid] + fpart[0][1][tid] + fpart[0][2][tid] + fpart[0][3][tid];
    f2[rb + tid] = fpart[1][0][tid] + fpart[1][1][tid] + fpart[1][2][tid] + fpart[1][3][tid];
  }
}

// ---------------- K2: softmax + h'=elu(att@h) + g = h'@W0 (fused) -----------
__launch_bounds__(128)
__global__ void k_gather(const int* __restrict__ nnzg, const u16* __restrict__ idxg,
                         const float* __restrict__ f1, const float* __restrict__ f2,
                         const u16* __restrict__ hb, const float* __restrict__ W0,
                         float* __restrict__ g){
  int i = blockIdx.x;
  int tid = threadIdx.x, lane = tid & 63, wid = tid >> 6;
  __shared__ int s_j[CAP];
  __shared__ float s_w[CAP];
  __shared__ float s_red[4];
  __shared__ float s_hp[FO];
  __shared__ float s_part[120];
  int nnz = nnzg[i];
  for (int t = tid; t < nnz; t += 128) s_j[t] = idxg[(size_t)i * CAP + t];
  __syncthreads();
  float fi = f1[i];
  float e0 = -1e30f, e1 = -1e30f;
  if (tid < nnz)       { float e = fi + f2[s_j[tid]];       e0 = e > 0.f ? e : ALPHA * e; }
  if (tid + 128 < nnz) { float e = fi + f2[s_j[tid + 128]]; e1 = e > 0.f ? e : ALPHA * e; }
  float m = fmaxf(e0, e1);
  #pragma unroll
  for (int o = 32; o; o >>= 1) m = fmaxf(m, __shfl_xor(m, o));
  if (lane == 0) s_red[wid] = m;
  __syncthreads();
  m = fmaxf(s_red[0], s_red[1]);
  float p0 = (tid < nnz)       ? __expf(e0 - m) : 0.f;
  float p1 = (tid + 128 < nnz) ? __expf(e1 - m) : 0.f;
  float s = p0 + p1;
  #pragma unroll
  for (int o = 32; o; o >>= 1) s += __shfl_xor(s, o);
  if (lane == 0) s_red[2 + wid] = s;
  __syncthreads();
  float rs = 1.0f / (s_red[2] + s_red[3]);
  if (tid < nnz)       s_w[tid]       = p0 * rs;
  if (tid + 128 < nnz) s_w[tid + 128] = p1 * rs;
  __syncthreads();
  if (tid < 100) {
    float ax = 0.f, ay = 0.f;
    int jj = 0;
    for (; jj + 8 <= nnz; jj += 8) {
      #pragma unroll
      for (int q = 0; q < 8; q++) {
        int j = s_j[jj + q];
        float w = s_w[jj + q];
        u32 hv = *(const u32*)&hb[(size_t)j * FO + 2 * tid];
        ax = fmaf(w, bf2f((u16)(hv & 0xffffu)), ax);
        ay = fmaf(w, bf2f((u16)(hv >> 16)), ay);
      }
    }
    for (; jj < nnz; jj++) {
      int j = s_j[jj];
      float w = s_w[jj];
      u32 hv = *(const u32*)&hb[(size_t)j * FO + 2 * tid];
      ax = fmaf(w, bf2f((u16)(hv & 0xffffu)), ax);
      ay = fmaf(w, bf2f((u16)(hv >> 16)), ay);
    }
    s_hp[2 * tid]     = ax > 0.f ? ax : expm1f(ax);
    s_hp[2 * tid + 1] = ay > 0.f ? ay : expm1f(ay);
  }
  __syncthreads();
  if (tid < 120) {
    int c = tid % 20, dg = tid / 20;
    float acc = 0.f;
    for (int d = dg; d < FO; d += 6)
      acc = fmaf(s_hp[d], W0[d * CO + c], acc);
    s_part[tid] = acc;
  }
  __syncthreads();
  if (tid < 20) {
    float a = s_part[tid] + s_part[tid + 20] + s_part[tid + 40]
            + s_part[tid + 60] + s_part[tid + 80] + s_part[tid + 100];
    g[(size_t)i * CO + tid] = a;
  }
}

// ---------------- K3: out = support @ g  (sparse rep, LDS-staged) ------------
__launch_bounds__(256)
__global__ void k_out(const int* __restrict__ nnzg, const u16* __restrict__ idxg,
                      const float* __restrict__ valg, const float* __restrict__ g,
                      float* __restrict__ out){
  int tid = threadIdx.x, lane = tid & 63, wid = tid >> 6;
  int i = blockIdx.x * 4 + wid;
  __shared__ int s_j[4][CAP];
  __shared__ float s_w[4][CAP];
  int nnz = nnzg[i];
  for (int t = lane; t < nnz; t += 64) {
    s_j[wid][t] = idxg[(size_t)i * CAP + t];
    s_w[wid][t] = valg[(size_t)i * CAP + t];
  }
  __syncthreads();
  int c = lane % 20, grp = lane / 20;
  float acc = 0.f;
  if (grp < 3) {
    for (int jj = grp; jj < nnz; jj += 3)
      acc = fmaf(s_w[wid][jj], g[(size_t)s_j[wid][jj] * CO + c], acc);
  }
  float b1 = __shfl(acc, lane + 20);
  float b2 = __shfl(acc, lane + 40);
  if (lane < 20) out[(size_t)i * CO + lane] = acc + b1 + b2;
}

extern "C" void kernel_launch(void* const* d_in, const int* in_sizes, int n_in,
                              void* d_out, int out_size, void* d_ws, size_t ws_size,
                              hipStream_t stream) {
  (void)in_sizes; (void)n_in; (void)out_size; (void)ws_size;
  const float* x       = (const float*)d_in[0];
  const float* support = (const float*)d_in[1];
  const float* W       = (const float*)d_in[2];
  const float* a1      = (const float*)d_in[3];
  const float* a2      = (const float*)d_in[4];
  const float* W0      = (const float*)d_in[5];
  char* ws = (char*)d_ws;
  float* f1   = (float*)(ws + 0);          // 8192*4      = 32768
  float* f2   = (float*)(ws + 32768);      // 8192*4      = 32768
  u16*   hb   = (u16*)  (ws + 65536);      // 8192*200*2  = 3276800
  float* g    = (float*)(ws + 3342336);    // 8192*20*4   = 655360
  int*   nnzg = (int*)  (ws + 3997696);    // 8192*4      = 32768
  u16*   idxg = (u16*)  (ws + 4030464);    // 8192*256*2  = 4194304
  float* valg = (float*)(ws + 8224768);    // 8192*256*4  = 8388608
  float* outp = (float*)d_out;

  k_main  <<<GEMM_BLOCKS + COMPACT_BLOCKS, 256, 0, stream>>>(support, x, W, a1, a2,
                                                             hb, f1, f2, nnzg, idxg, valg);
  k_gather<<<NN,     128, 0, stream>>>(nnzg, idxg, f1, f2, hb, W0, g);
  k_out   <<<NN / 4, 256, 0, stream>>>(nnzg, idxg, valg, g, outp);
}